// Round 2
// baseline (615.727 us; speedup 1.0000x reference)
//
#include <hip/hip_runtime.h>
#include <hip/hip_bf16.h>

// SelfAttention: x[8,256,48,48] fp32; wq/wk/wv[256,256] fp32.
// out = x + attn(softmax(q^T k) , v), q=wq@x etc (1x1 convs).
// B=8, C=256, N=2304. fp16 MFMA path (bf16 gave absmax 0.33 > 0.147 thr:
// unscaled logits sigma~16 -> softmax amplifies input rounding; fp16's
// 10-bit mantissa cuts it 8x).
//
// ws layout (ushort/fp16 elems): wq_h[65536] wk_h[65536] wv_h[65536]
//   Qt[B*N*C] (token-major), Kt[B*N*C] (token-major), Vf[B*C*N] (feature-major)

#define DEVI __device__ __forceinline__

typedef _Float16 f16x8 __attribute__((ext_vector_type(8)));
typedef float f32x4 __attribute__((ext_vector_type(4)));

constexpr int Bn = 8, Cn = 256, Nn = 48 * 48;   // 2304

DEVI unsigned short f2h(float f) {              // fp32 -> fp16 (RNE)
  _Float16 h = (_Float16)f;
  return __builtin_bit_cast(unsigned short, h);
}

#define MFMA16(a, b, c) __builtin_amdgcn_mfma_f32_16x16x32_f16((a), (b), (c), 0, 0, 0)

__global__ __launch_bounds__(256) void cvt_w(const float* __restrict__ wq,
                                             const float* __restrict__ wk,
                                             const float* __restrict__ wv,
                                             unsigned short* __restrict__ o) {
  int idx = blockIdx.x * 256 + threadIdx.x;     // 3*65536 total
  const float* s = (idx < Cn * Cn) ? wq : (idx < 2 * Cn * Cn) ? wk : wv;
  o[idx] = f2h(s[idx & (Cn * Cn - 1)]);
}

// ---------------- QKV projection ----------------
// grid (N/64, B), 256 thr (4 waves, 16 tokens each).
// Fragment layout (gfx950 16x16x32): A/B lane l: row/col = l&15, k = 8*(l>>4)+j (contig).
// C/D: col = l&15, row = 4*(l>>4)+r.
__global__ __launch_bounds__(256) void qkv_proj(
    const float* __restrict__ x,
    const unsigned short* __restrict__ wqb, const unsigned short* __restrict__ wkb,
    const unsigned short* __restrict__ wvb,
    unsigned short* __restrict__ Qt, unsigned short* __restrict__ Kt,
    unsigned short* __restrict__ Vf) {
  __shared__ unsigned short xT[64][264];        // [token][c], +8 pad
  const int tid = threadIdx.x;
  const int n0 = blockIdx.x * 64;
  const int b = blockIdx.y;
  const float* xb = x + (size_t)b * Cn * Nn;
  {
    int cbase = tid >> 4;
    int nn = (tid & 15) * 4;
#pragma unroll
    for (int it = 0; it < 16; ++it) {
      int c = cbase + 16 * it;
      float4 v = *(const float4*)(xb + (size_t)c * Nn + n0 + nn);
      xT[nn + 0][c] = f2h(v.x);
      xT[nn + 1][c] = f2h(v.y);
      xT[nn + 2][c] = f2h(v.z);
      xT[nn + 3][c] = f2h(v.w);
    }
  }
  __syncthreads();
  const int lane = tid & 63, w = tid >> 6;
  const int i = lane & 15, g = lane >> 4;
  f16x8 xf[8];                                  // x^T frags: A for Q/K, B for V
#pragma unroll
  for (int ks = 0; ks < 8; ++ks)
    xf[ks] = *(const f16x8*)(&xT[w * 16 + i][32 * ks + 8 * g]);

  const size_t tokbase = (size_t)b * Nn + n0 + w * 16;
#pragma unroll 1
  for (int p = 0; p < 2; ++p) {                 // Q, K -> token-major [N][C]
    const unsigned short* wm = p ? wkb : wqb;
    unsigned short* op = p ? Kt : Qt;
    for (int ot = 0; ot < 16; ++ot) {
      f32x4 acc = {0.f, 0.f, 0.f, 0.f};
      const unsigned short* wr = wm + (ot * 16 + i) * Cn + 8 * g;
#pragma unroll
      for (int ks = 0; ks < 8; ++ks)
        acc = MFMA16(xf[ks], *(const f16x8*)(wr + 32 * ks), acc);
#pragma unroll
      for (int r = 0; r < 4; ++r)
        op[(tokbase + 4 * g + r) * Cn + ot * 16 + i] = f2h(acc[r]);
    }
  }
  for (int ot = 0; ot < 16; ++ot) {             // V -> feature-major [C][N]
    f32x4 acc = {0.f, 0.f, 0.f, 0.f};
    const unsigned short* wr = wvb + (ot * 16 + i) * Cn + 8 * g;
#pragma unroll
    for (int ks = 0; ks < 8; ++ks)
      acc = MFMA16(*(const f16x8*)(wr + 32 * ks), xf[ks], acc);
#pragma unroll
    for (int r = 0; r < 4; ++r)
      Vf[((size_t)b * Cn + ot * 16 + 4 * g + r) * Nn + n0 + w * 16 + i] = f2h(acc[r]);
  }
}

// ---------------- flash attention + residual ----------------
// grid B*N/64, 256 thr (4 waves x 16 queries). 32-key chunks.
// Swapped S: D[key][query] = mfma(Kfrag, Qfrag) -> lane owns query (l&15), 8 keys.
__global__ __launch_bounds__(256) void attn_kernel(
    const float* __restrict__ x, const unsigned short* __restrict__ Qt,
    const unsigned short* __restrict__ Kt, const unsigned short* __restrict__ Vf,
    float* __restrict__ out) {
  __shared__ float OT[128][65];
  int bid = (blockIdx.x & 7) * 36 + (blockIdx.x >> 3);  // XCD swizzle, 288=8*36
  const int b = bid / 36, qt = bid - 36 * b;
  const int n0 = qt * 64;
  const int tid = threadIdx.x, lane = tid & 63, w = tid >> 6;
  const int i = lane & 15, g = lane >> 4;
  const int iw = n0 + w * 16;

  const unsigned short* Qb = Qt + ((size_t)b * Nn + iw + i) * Cn + 8 * g;
  f16x8 qf[8];
#pragma unroll
  for (int ks = 0; ks < 8; ++ks) qf[ks] = *(const f16x8*)(Qb + 32 * ks);

  f32x4 acc[16];
#pragma unroll
  for (int ct = 0; ct < 16; ++ct) acc[ct] = (f32x4){0.f, 0.f, 0.f, 0.f};
  float m = -1e30f, lsum = 0.f;

  const unsigned short* Kb = Kt + (size_t)b * Nn * Cn + i * Cn + 8 * g;
  const unsigned short* Vb = Vf + (size_t)b * Cn * Nn + (size_t)i * Nn + 8 * g;

  for (int j0 = 0; j0 < Nn; j0 += 32) {
    const unsigned short* kp = Kb + (size_t)j0 * Cn;
    f32x4 d0 = {0.f, 0.f, 0.f, 0.f}, d1 = {0.f, 0.f, 0.f, 0.f};
#pragma unroll
    for (int ks = 0; ks < 8; ++ks) {
      d0 = MFMA16(*(const f16x8*)(kp + 32 * ks), qf[ks], d0);
      d1 = MFMA16(*(const f16x8*)(kp + 16 * Cn + 32 * ks), qf[ks], d1);
    }
    // lane holds S[keys 4g+r | 16+4g+r][query i]
    float mx = fmaxf(fmaxf(fmaxf(d0[0], d0[1]), fmaxf(d0[2], d0[3])),
                     fmaxf(fmaxf(d1[0], d1[1]), fmaxf(d1[2], d1[3])));
    mx = fmaxf(mx, __shfl_xor(mx, 16));
    mx = fmaxf(mx, __shfl_xor(mx, 32));
    if (__any(mx > m + 8.f)) {                  // defer-max (THR=8)
      float mnew = fmaxf(m, mx);
      float alpha = __expf(m - mnew);
      m = mnew;
      float ar0 = __shfl(alpha, 4 * g + 0), ar1 = __shfl(alpha, 4 * g + 1);
      float ar2 = __shfl(alpha, 4 * g + 2), ar3 = __shfl(alpha, 4 * g + 3);
      lsum *= alpha;
#pragma unroll
      for (int ct = 0; ct < 16; ++ct) {
        acc[ct][0] *= ar0; acc[ct][1] *= ar1; acc[ct][2] *= ar2; acc[ct][3] *= ar3;
      }
    }
    float p0[4], p1[4];
#pragma unroll
    for (int r = 0; r < 4; ++r) {
      p0[r] = __expf(d0[r] - m);
      p1[r] = __expf(d1[r] - m);
    }
    float cs = (p0[0] + p0[1]) + (p0[2] + p0[3]) + (p1[0] + p1[1]) + (p1[2] + p1[3]);
    cs += __shfl_xor(cs, 16);
    cs += __shfl_xor(cs, 32);
    lsum += cs;
    // P A-frag: lane (i,g) needs P[query i][keys 8g..8g+7]
    const int srcA = i + 16 * ((2 * g) & 3);
    const int srcB = i + 16 * ((2 * g + 1) & 3);
    union { unsigned short u[8]; f16x8 v; } pu;
#pragma unroll
    for (int r = 0; r < 4; ++r) {
      float a0s = __shfl(p0[r], srcA);
      float a1s = __shfl(p1[r], srcA);
      float b0s = __shfl(p0[r], srcB);
      float b1s = __shfl(p1[r], srcB);
      pu.u[r] = f2h(g < 2 ? a0s : a1s);
      pu.u[4 + r] = f2h(g < 2 ? b0s : b1s);
    }
    f16x8 pf = pu.v;
    const unsigned short* vp = Vb + j0;
#pragma unroll
    for (int ct = 0; ct < 16; ++ct)
      acc[ct] = MFMA16(pf, *(const f16x8*)(vp + (size_t)ct * 16 * Nn), acc[ct]);
  }
  // normalize rows (acc row r is query 4g+r), stream out via LDS transpose
  float l0 = __shfl(lsum, 4 * g + 0), l1 = __shfl(lsum, 4 * g + 1);
  float l2 = __shfl(lsum, 4 * g + 2), l3 = __shfl(lsum, 4 * g + 3);
  f32x4 rl = {1.f / l0, 1.f / l1, 1.f / l2, 1.f / l3};
  const float* xb = x + (size_t)b * Cn * Nn;
  float* ob = out + (size_t)b * Cn * Nn;
#pragma unroll 1
  for (int h = 0; h < 2; ++h) {
    if (h) __syncthreads();
#pragma unroll
    for (int ctl = 0; ctl < 8; ++ctl) {
      int ct = 8 * h + ctl;
#pragma unroll
      for (int r = 0; r < 4; ++r)
        OT[ctl * 16 + i][w * 16 + 4 * g + r] = acc[ct][r] * rl[r];
    }
    __syncthreads();
    int c0 = w * 32;
    for (int cc = 0; cc < 32; ++cc) {
      int c = 128 * h + c0 + cc;
      size_t idx = (size_t)c * Nn + n0 + lane;
      ob[idx] = xb[idx] + OT[c0 + cc][lane];
    }
  }
}

extern "C" void kernel_launch(void* const* d_in, const int* in_sizes, int n_in,
                              void* d_out, int out_size, void* d_ws, size_t ws_size,
                              hipStream_t stream) {
  const float* x = (const float*)d_in[0];
  const float* wq = (const float*)d_in[1];
  const float* wk = (const float*)d_in[2];
  const float* wv = (const float*)d_in[3];
  float* out = (float*)d_out;

  unsigned short* wqb = (unsigned short*)d_ws;
  unsigned short* wkb = wqb + Cn * Cn;
  unsigned short* wvb = wkb + Cn * Cn;
  unsigned short* Qt = wvb + Cn * Cn;
  unsigned short* Kt = Qt + (size_t)Bn * Nn * Cn;
  unsigned short* Vf = Kt + (size_t)Bn * Nn * Cn;

  hipLaunchKernelGGL(cvt_w, dim3(3 * Cn * Cn / 256), dim3(256), 0, stream, wq, wk, wv, wqb);
  hipLaunchKernelGGL(qkv_proj, dim3(Nn / 64, Bn), dim3(256), 0, stream,
                     x, wqb, wkb, wvb, Qt, Kt, Vf);
  hipLaunchKernelGGL(attn_kernel, dim3(Bn * Nn / 64), dim3(256), 0, stream,
                     x, Qt, Kt, Vf, out);
}

// Round 3
// 473.018 us; speedup vs baseline: 1.3017x; 1.3017x over previous
//
#include <hip/hip_runtime.h>
#include <hip/hip_bf16.h>

// SelfAttention: x[8,256,48,48] fp32; wq/wk/wv[256,256] fp32.
// out = x + attn(softmax(q^T k), v). B=8, C=256, N=2304. fp16 MFMA path.
//
// R2: attn was latency-bound (MfmaUtil 3.3%, Occupancy 8.5%, 1 wave/SIMD).
// Fix: flash split-K (splits=4 -> 1152 blocks, ~4.5 waves/SIMD) writing
// unnormalized partials (acc,m,l) to ws; combine kernel merges + residual.
// qkv_proj split over z in {Q,K,V} -> 864 blocks.
//
// ws layout: wq_h/wk_h/wv_h [65536 each, fp16]; Qt,Kt [B*N*C fp16 token-major];
// Vf [B*C*N fp16 feature-major]; P [splits][B][C][N] f32; ml [splits][B][N][2] f32.

#define DEVI __device__ __forceinline__

typedef _Float16 f16x8 __attribute__((ext_vector_type(8)));
typedef float f32x4 __attribute__((ext_vector_type(4)));

constexpr int Bn = 8, Cn = 256, Nn = 48 * 48;   // 2304

DEVI unsigned short f2h(float f) {              // fp32 -> fp16 (RNE)
  _Float16 h = (_Float16)f;
  return __builtin_bit_cast(unsigned short, h);
}

#define MFMA16(a, b, c) __builtin_amdgcn_mfma_f32_16x16x32_f16((a), (b), (c), 0, 0, 0)

__global__ __launch_bounds__(256) void cvt_w(const float* __restrict__ wq,
                                             const float* __restrict__ wk,
                                             const float* __restrict__ wv,
                                             unsigned short* __restrict__ o) {
  int idx = blockIdx.x * 256 + threadIdx.x;     // 3*65536 total
  const float* s = (idx < Cn * Cn) ? wq : (idx < 2 * Cn * Cn) ? wk : wv;
  o[idx] = f2h(s[idx & (Cn * Cn - 1)]);
}

// ---------------- QKV projection ----------------
// grid (N/64, B, 3), 256 thr (4 waves, 16 tokens each). z: 0=Q 1=K 2=V.
// A/B frag lane l: row/col = l&15, k = 8*(l>>4)+j. C/D: col=l&15, row=4*(l>>4)+r.
__global__ __launch_bounds__(256) void qkv_proj(
    const float* __restrict__ x,
    const unsigned short* __restrict__ wqb, const unsigned short* __restrict__ wkb,
    const unsigned short* __restrict__ wvb,
    unsigned short* __restrict__ Qt, unsigned short* __restrict__ Kt,
    unsigned short* __restrict__ Vf) {
  __shared__ unsigned short xT[64][264];        // [token][c], +8 pad
  const int tid = threadIdx.x;
  const int n0 = blockIdx.x * 64;
  const int b = blockIdx.y;
  const int z = blockIdx.z;
  const float* xb = x + (size_t)b * Cn * Nn;
  {
    int cbase = tid >> 4;
    int nn = (tid & 15) * 4;
#pragma unroll
    for (int it = 0; it < 16; ++it) {
      int c = cbase + 16 * it;
      float4 v = *(const float4*)(xb + (size_t)c * Nn + n0 + nn);
      xT[nn + 0][c] = f2h(v.x);
      xT[nn + 1][c] = f2h(v.y);
      xT[nn + 2][c] = f2h(v.z);
      xT[nn + 3][c] = f2h(v.w);
    }
  }
  __syncthreads();
  const int lane = tid & 63, w = tid >> 6;
  const int i = lane & 15, g = lane >> 4;
  f16x8 xf[8];                                  // x^T frags
#pragma unroll
  for (int ks = 0; ks < 8; ++ks)
    xf[ks] = *(const f16x8*)(&xT[w * 16 + i][32 * ks + 8 * g]);

  if (z < 2) {                                  // Q or K -> token-major [N][C]
    const unsigned short* wm = z ? wkb : wqb;
    unsigned short* op = z ? Kt : Qt;
    const size_t tokbase = (size_t)b * Nn + n0 + w * 16;
    for (int ot = 0; ot < 16; ++ot) {
      f32x4 acc = {0.f, 0.f, 0.f, 0.f};
      const unsigned short* wr = wm + (ot * 16 + i) * Cn + 8 * g;
#pragma unroll
      for (int ks = 0; ks < 8; ++ks)
        acc = MFMA16(xf[ks], *(const f16x8*)(wr + 32 * ks), acc);
#pragma unroll
      for (int r = 0; r < 4; ++r)
        op[(tokbase + 4 * g + r) * Cn + ot * 16 + i] = f2h(acc[r]);
    }
  } else {                                      // V -> feature-major [C][N]
    for (int ot = 0; ot < 16; ++ot) {
      f32x4 acc = {0.f, 0.f, 0.f, 0.f};
      const unsigned short* wr = wvb + (ot * 16 + i) * Cn + 8 * g;
#pragma unroll
      for (int ks = 0; ks < 8; ++ks)
        acc = MFMA16(*(const f16x8*)(wr + 32 * ks), xf[ks], acc);
#pragma unroll
      for (int r = 0; r < 4; ++r)
        Vf[((size_t)b * Cn + ot * 16 + 4 * g + r) * Nn + n0 + w * 16 + i] = f2h(acc[r]);
    }
  }
}

// ---------------- flash attention, split-K, partial outputs ----------------
// grid Bn*splits*36 (1D), 256 thr (4 waves x 16 queries). 32-key chunks.
// Swapped S: D[key][query] = mfma(Kfrag, Qfrag) -> lane owns query (l&15), 8 keys.
// Writes P[s][b][c][n] (unnormalized, scaled to local m) and ml[s][b][n]={m,l}.
__global__ __launch_bounds__(256, 4) void attn_split(
    const unsigned short* __restrict__ Qt, const unsigned short* __restrict__ Kt,
    const unsigned short* __restrict__ Vf,
    float* __restrict__ P, float* __restrict__ ml, int splits) {
  const int nblk = gridDim.x;                   // divisible by 8
  const int cpx = nblk >> 3;
  const int swz = (blockIdx.x & 7) * cpx + (blockIdx.x >> 3);  // XCD chunked
  const int per_b = splits * 36;
  const int b = swz / per_b;
  const int rem = swz - b * per_b;
  const int s = rem / 36;
  const int qt = rem - s * 36;
  const int n0 = qt * 64;
  const int kn = Nn / splits, k0 = s * kn;

  const int tid = threadIdx.x, lane = tid & 63, w = tid >> 6;
  const int i = lane & 15, g = lane >> 4;
  const int iw = n0 + w * 16;

  const unsigned short* Qb = Qt + ((size_t)b * Nn + iw + i) * Cn + 8 * g;
  f16x8 qf[8];
#pragma unroll
  for (int ks = 0; ks < 8; ++ks) qf[ks] = *(const f16x8*)(Qb + 32 * ks);

  f32x4 acc[16];
#pragma unroll
  for (int ct = 0; ct < 16; ++ct) acc[ct] = (f32x4){0.f, 0.f, 0.f, 0.f};
  float m = -1e30f, lsum = 0.f;

  const unsigned short* Kb = Kt + (size_t)b * Nn * Cn + i * Cn + 8 * g;
  const unsigned short* Vb = Vf + (size_t)b * Cn * Nn + (size_t)i * Nn + 8 * g;

  for (int j0 = k0; j0 < k0 + kn; j0 += 32) {
    const unsigned short* kp = Kb + (size_t)j0 * Cn;
    f32x4 d0 = {0.f, 0.f, 0.f, 0.f}, d1 = {0.f, 0.f, 0.f, 0.f};
#pragma unroll
    for (int ks = 0; ks < 8; ++ks) {
      d0 = MFMA16(*(const f16x8*)(kp + 32 * ks), qf[ks], d0);
      d1 = MFMA16(*(const f16x8*)(kp + 16 * Cn + 32 * ks), qf[ks], d1);
    }
    // lane holds S[keys 4g+r | 16+4g+r][query i]
    float mx = fmaxf(fmaxf(fmaxf(d0[0], d0[1]), fmaxf(d0[2], d0[3])),
                     fmaxf(fmaxf(d1[0], d1[1]), fmaxf(d1[2], d1[3])));
    mx = fmaxf(mx, __shfl_xor(mx, 16));
    mx = fmaxf(mx, __shfl_xor(mx, 32));
    if (__any(mx > m + 8.f)) {                  // defer-max (THR=8)
      float mnew = fmaxf(m, mx);
      float alpha = __expf(m - mnew);
      m = mnew;
      float ar0 = __shfl(alpha, 4 * g + 0), ar1 = __shfl(alpha, 4 * g + 1);
      float ar2 = __shfl(alpha, 4 * g + 2), ar3 = __shfl(alpha, 4 * g + 3);
      lsum *= alpha;
#pragma unroll
      for (int ct = 0; ct < 16; ++ct) {
        acc[ct][0] *= ar0; acc[ct][1] *= ar1; acc[ct][2] *= ar2; acc[ct][3] *= ar3;
      }
    }
    float p0[4], p1[4];
#pragma unroll
    for (int r = 0; r < 4; ++r) {
      p0[r] = __expf(d0[r] - m);
      p1[r] = __expf(d1[r] - m);
    }
    float cs = (p0[0] + p0[1]) + (p0[2] + p0[3]) + (p1[0] + p1[1]) + (p1[2] + p1[3]);
    cs += __shfl_xor(cs, 16);
    cs += __shfl_xor(cs, 32);
    lsum += cs;
    // P A-frag: lane (i,g) needs P[query i][keys 8g..8g+7]
    const int srcA = i + 16 * ((2 * g) & 3);
    const int srcB = i + 16 * ((2 * g + 1) & 3);
    union { unsigned short u[8]; f16x8 v; } pu;
#pragma unroll
    for (int r = 0; r < 4; ++r) {
      float a0s = __shfl(p0[r], srcA);
      float a1s = __shfl(p1[r], srcA);
      float b0s = __shfl(p0[r], srcB);
      float b1s = __shfl(p1[r], srcB);
      pu.u[r] = f2h(g < 2 ? a0s : a1s);
      pu.u[4 + r] = f2h(g < 2 ? b0s : b1s);
    }
    f16x8 pf = pu.v;
    const unsigned short* vp = Vb + j0;
#pragma unroll
    for (int ct = 0; ct < 16; ++ct)
      acc[ct] = MFMA16(pf, *(const f16x8*)(vp + (size_t)ct * 16 * Nn), acc[ct]);
  }
  // epilogue: raw partial stores, c-major. acc[ct][r] = (q iw+ w16+4g+r? no:
  // query index within wave = 4g+r -> n = n0 + w*16 + 4g + r; c = ct*16 + i.
  float* Pb = P + ((size_t)(s * Bn + b) * Cn) * Nn;
#pragma unroll
  for (int ct = 0; ct < 16; ++ct)
    *(f32x4*)&Pb[(size_t)(ct * 16 + i) * Nn + n0 + w * 16 + 4 * g] = acc[ct];
  if (g == 0) {
    float2 v = make_float2(m, lsum);
    *(float2*)&ml[((size_t)(s * Bn + b) * Nn + iw + i) * 2] = v;
  }
}

// ---------------- combine partials + normalize + residual ----------------
// grid Bn*Nn/32, 256 thr. Block: (b, 32-n tile) x all 256 c.
__global__ __launch_bounds__(256) void combine_k(
    const float* __restrict__ x, const float* __restrict__ P,
    const float* __restrict__ ml, float* __restrict__ out, int splits) {
  __shared__ float sc[4][32];
  const int tpb = Nn / 32;                      // 72
  const int b = blockIdx.x / tpb;
  const int n0 = (blockIdx.x - b * tpb) * 32;
  const int t = threadIdx.x;
  if (t < 32) {
    const int n = n0 + t;
    const size_t sstr = (size_t)Bn * Nn * 2;
    const float* mlb = ml + ((size_t)b * Nn + n) * 2;
    float m0 = mlb[0], l0 = mlb[1];
    float m1 = -1e30f, l1 = 0.f, m2 = -1e30f, l2 = 0.f, m3 = -1e30f, l3 = 0.f;
    if (splits > 1) { m1 = mlb[sstr]; l1 = mlb[sstr + 1]; }
    if (splits > 2) { m2 = mlb[2 * sstr]; l2 = mlb[2 * sstr + 1]; }
    if (splits > 3) { m3 = mlb[3 * sstr]; l3 = mlb[3 * sstr + 1]; }
    float M = fmaxf(fmaxf(m0, m1), fmaxf(m2, m3));
    float f0 = __expf(m0 - M), f1 = __expf(m1 - M);
    float f2 = __expf(m2 - M), f3 = __expf(m3 - M);
    float rden = 1.f / (f0 * l0 + f1 * l1 + f2 * l2 + f3 * l3);
    sc[0][t] = f0 * rden; sc[1][t] = f1 * rden;
    sc[2][t] = f2 * rden; sc[3][t] = f3 * rden;
  }
  __syncthreads();
  const int nl4 = (t & 7) * 4, c0 = t >> 3;
  const size_t pstr = (size_t)Bn * Cn * Nn;
  const float* xb = x + (size_t)b * Cn * Nn;
  float* ob = out + (size_t)b * Cn * Nn;
#pragma unroll
  for (int k = 0; k < 8; ++k) {
    const int c = c0 + 32 * k;
    const float* Pp = P + ((size_t)b * Cn + c) * Nn + n0 + nl4;
    f32x4 a = {0.f, 0.f, 0.f, 0.f};
    for (int s2 = 0; s2 < splits; ++s2) {
      f32x4 p = *(const f32x4*)(Pp + s2 * pstr);
      f32x4 sv = *(const f32x4*)&sc[s2][nl4];
      a += sv * p;
    }
    f32x4 xv = *(const f32x4*)(xb + (size_t)c * Nn + n0 + nl4);
    *(f32x4*)(ob + (size_t)c * Nn + n0 + nl4) = xv + a;
  }
}

// ---------------- fallback: self-contained attention (ws too small) --------
__global__ __launch_bounds__(256) void attn_kernel(
    const float* __restrict__ x, const unsigned short* __restrict__ Qt,
    const unsigned short* __restrict__ Kt, const unsigned short* __restrict__ Vf,
    float* __restrict__ out) {
  __shared__ float OT[128][65];
  int bid = (blockIdx.x & 7) * 36 + (blockIdx.x >> 3);
  const int b = bid / 36, qt = bid - 36 * b;
  const int n0 = qt * 64;
  const int tid = threadIdx.x, lane = tid & 63, w = tid >> 6;
  const int i = lane & 15, g = lane >> 4;
  const int iw = n0 + w * 16;
  const unsigned short* Qb = Qt + ((size_t)b * Nn + iw + i) * Cn + 8 * g;
  f16x8 qf[8];
#pragma unroll
  for (int ks = 0; ks < 8; ++ks) qf[ks] = *(const f16x8*)(Qb + 32 * ks);
  f32x4 acc[16];
#pragma unroll
  for (int ct = 0; ct < 16; ++ct) acc[ct] = (f32x4){0.f, 0.f, 0.f, 0.f};
  float m = -1e30f, lsum = 0.f;
  const unsigned short* Kb = Kt + (size_t)b * Nn * Cn + i * Cn + 8 * g;
  const unsigned short* Vb = Vf + (size_t)b * Cn * Nn + (size_t)i * Nn + 8 * g;
  for (int j0 = 0; j0 < Nn; j0 += 32) {
    const unsigned short* kp = Kb + (size_t)j0 * Cn;
    f32x4 d0 = {0.f, 0.f, 0.f, 0.f}, d1 = {0.f, 0.f, 0.f, 0.f};
#pragma unroll
    for (int ks = 0; ks < 8; ++ks) {
      d0 = MFMA16(*(const f16x8*)(kp + 32 * ks), qf[ks], d0);
      d1 = MFMA16(*(const f16x8*)(kp + 16 * Cn + 32 * ks), qf[ks], d1);
    }
    float mx = fmaxf(fmaxf(fmaxf(d0[0], d0[1]), fmaxf(d0[2], d0[3])),
                     fmaxf(fmaxf(d1[0], d1[1]), fmaxf(d1[2], d1[3])));
    mx = fmaxf(mx, __shfl_xor(mx, 16));
    mx = fmaxf(mx, __shfl_xor(mx, 32));
    if (__any(mx > m + 8.f)) {
      float mnew = fmaxf(m, mx);
      float alpha = __expf(m - mnew);
      m = mnew;
      float ar0 = __shfl(alpha, 4 * g + 0), ar1 = __shfl(alpha, 4 * g + 1);
      float ar2 = __shfl(alpha, 4 * g + 2), ar3 = __shfl(alpha, 4 * g + 3);
      lsum *= alpha;
#pragma unroll
      for (int ct = 0; ct < 16; ++ct) {
        acc[ct][0] *= ar0; acc[ct][1] *= ar1; acc[ct][2] *= ar2; acc[ct][3] *= ar3;
      }
    }
    float p0[4], p1[4];
#pragma unroll
    for (int r = 0; r < 4; ++r) {
      p0[r] = __expf(d0[r] - m);
      p1[r] = __expf(d1[r] - m);
    }
    float cs = (p0[0] + p0[1]) + (p0[2] + p0[3]) + (p1[0] + p1[1]) + (p1[2] + p1[3]);
    cs += __shfl_xor(cs, 16);
    cs += __shfl_xor(cs, 32);
    lsum += cs;
    const int srcA = i + 16 * ((2 * g) & 3);
    const int srcB = i + 16 * ((2 * g + 1) & 3);
    union { unsigned short u[8]; f16x8 v; } pu;
#pragma unroll
    for (int r = 0; r < 4; ++r) {
      float a0s = __shfl(p0[r], srcA);
      float a1s = __shfl(p1[r], srcA);
      float b0s = __shfl(p0[r], srcB);
      float b1s = __shfl(p1[r], srcB);
      pu.u[r] = f2h(g < 2 ? a0s : a1s);
      pu.u[4 + r] = f2h(g < 2 ? b0s : b1s);
    }
    f16x8 pf = pu.v;
    const unsigned short* vp = Vb + j0;
#pragma unroll
    for (int ct = 0; ct < 16; ++ct)
      acc[ct] = MFMA16(pf, *(const f16x8*)(vp + (size_t)ct * 16 * Nn), acc[ct]);
  }
  float l0 = __shfl(lsum, 4 * g + 0), l1 = __shfl(lsum, 4 * g + 1);
  float l2 = __shfl(lsum, 4 * g + 2), l3 = __shfl(lsum, 4 * g + 3);
  f32x4 rl = {1.f / l0, 1.f / l1, 1.f / l2, 1.f / l3};
  const float* xb = x + (size_t)b * Cn * Nn;
  float* ob = out + (size_t)b * Cn * Nn;
#pragma unroll 1
  for (int h = 0; h < 2; ++h) {
    if (h) __syncthreads();
#pragma unroll
    for (int ctl = 0; ctl < 8; ++ctl) {
      int ct = 8 * h + ctl;
#pragma unroll
      for (int r = 0; r < 4; ++r)
        OT[ctl * 16 + i][w * 16 + 4 * g + r] = acc[ct][r] * rl[r];
    }
    __syncthreads();
    int c0 = w * 32;
    for (int cc = 0; cc < 32; ++cc) {
      int c = 128 * h + c0 + cc;
      size_t idx = (size_t)c * Nn + n0 + lane;
      ob[idx] = xb[idx] + OT[c0 + cc][lane];
    }
  }
}

extern "C" void kernel_launch(void* const* d_in, const int* in_sizes, int n_in,
                              void* d_out, int out_size, void* d_ws, size_t ws_size,
                              hipStream_t stream) {
  const float* x = (const float*)d_in[0];
  const float* wq = (const float*)d_in[1];
  const float* wk = (const float*)d_in[2];
  const float* wv = (const float*)d_in[3];
  float* out = (float*)d_out;

  unsigned short* wqb = (unsigned short*)d_ws;
  unsigned short* wkb = wqb + Cn * Cn;
  unsigned short* wvb = wkb + Cn * Cn;
  unsigned short* Qt = wvb + Cn * Cn;
  unsigned short* Kt = Qt + (size_t)Bn * Nn * Cn;
  unsigned short* Vf = Kt + (size_t)Bn * Nn * Cn;
  const size_t baseB = (size_t)(3 * Cn * Cn + 3 * (size_t)Bn * Nn * Cn) * 2;
  const size_t perSplitB = (size_t)Bn * Nn * Cn * 4 + (size_t)Bn * Nn * 2 * 4;

  int splits = 0;
  if (baseB + 4 * perSplitB <= ws_size) splits = 4;
  else if (baseB + 2 * perSplitB <= ws_size) splits = 2;
  else if (baseB + 1 * perSplitB <= ws_size) splits = 1;

  hipLaunchKernelGGL(cvt_w, dim3(3 * Cn * Cn / 256), dim3(256), 0, stream, wq, wk, wv, wqb);
  hipLaunchKernelGGL(qkv_proj, dim3(Nn / 64, Bn, 3), dim3(256), 0, stream,
                     x, wqb, wkb, wvb, Qt, Kt, Vf);
  if (splits) {
    float* P = (float*)((unsigned short*)d_ws + 3 * Cn * Cn + 3 * (size_t)Bn * Nn * Cn);
    float* ml = P + (size_t)splits * Bn * Nn * Cn;
    hipLaunchKernelGGL(attn_split, dim3(Bn * splits * 36), dim3(256), 0, stream,
                       Qt, Kt, Vf, P, ml, splits);
    hipLaunchKernelGGL(combine_k, dim3(Bn * Nn / 32), dim3(256), 0, stream,
                       x, P, ml, out, splits);
  } else {
    hipLaunchKernelGGL(attn_kernel, dim3(Bn * Nn / 64), dim3(256), 0, stream,
                       x, Qt, Kt, Vf, out);
  }
}

// Round 5
// 307.232 us; speedup vs baseline: 2.0041x; 1.5396x over previous
//
#include <hip/hip_runtime.h>
#include <hip/hip_bf16.h>

// SelfAttention: x[8,256,48,48] fp32; wq/wk/wv[256,256] fp32.
// out = x + attn(softmax(q^T k), v). B=8, C=256, N=2304. fp16 MFMA path.
//
// R3: attn_split was register-starved (VGPR=64): 32 loads/iter trickled
// through a tiny window -> ~50k cy per 32-key chunk, MfmaUtil 4.4%.
// Fix: 32x32x16 MFMA, 32 queries/wave, launch_bounds(256,2):
//   qf[16] resident (64 regs) + acc[8]xf32x16 (128) + streamed K/V.
//   Softmax: lane owns 1 query x 16 scores -> in-lane reduce + 1 shfl_xor(32).
//   P->B-frag: 8 cvt_pkrtz + 8 shfl_xor(32) (T12-style half exchange).
// R4: fix cvt_pkrtz return-type mismatch (__fp16 vector, bit_cast via auto).
//
// ws layout: wq_h/wk_h/wv_h [65536 each, fp16]; Qt,Kt [B*N*C fp16 token-major];
// Vf [B*C*N fp16 feature-major]; P [splits][B][C][N] f32; ml [splits][B][N][2] f32.

#define DEVI __device__ __forceinline__

typedef _Float16 f16x8 __attribute__((ext_vector_type(8)));
typedef float f32x4 __attribute__((ext_vector_type(4)));
typedef float f32x16 __attribute__((ext_vector_type(16)));

constexpr int Bn = 8, Cn = 256, Nn = 48 * 48;   // 2304

DEVI unsigned short f2h(float f) {              // fp32 -> fp16 (RNE)
  _Float16 h = (_Float16)f;
  return __builtin_bit_cast(unsigned short, h);
}
DEVI unsigned pk2(float a, float b) {           // pack 2 f32 -> f16x2 (RTZ)
  auto h = __builtin_amdgcn_cvt_pkrtz(a, b);
  return __builtin_bit_cast(unsigned, h);
}

#define MFMA16(a, b, c) __builtin_amdgcn_mfma_f32_16x16x32_f16((a), (b), (c), 0, 0, 0)
#define MFMA32(a, b, c) __builtin_amdgcn_mfma_f32_32x32x16_f16((a), (b), (c), 0, 0, 0)

__global__ __launch_bounds__(256) void cvt_w(const float* __restrict__ wq,
                                             const float* __restrict__ wk,
                                             const float* __restrict__ wv,
                                             unsigned short* __restrict__ o) {
  int idx = blockIdx.x * 256 + threadIdx.x;     // 3*65536 total
  const float* s = (idx < Cn * Cn) ? wq : (idx < 2 * Cn * Cn) ? wk : wv;
  o[idx] = f2h(s[idx & (Cn * Cn - 1)]);
}

// ---------------- QKV projection ----------------
// grid (N/64, B, 3), 256 thr (4 waves, 16 tokens each). z: 0=Q 1=K 2=V.
// 16x16x32 frags: A/B lane l: row/col=l&15, k=8*(l>>4)+j. C/D: col=l&15, row=4*(l>>4)+r.
__global__ __launch_bounds__(256) void qkv_proj(
    const float* __restrict__ x,
    const unsigned short* __restrict__ wqb, const unsigned short* __restrict__ wkb,
    const unsigned short* __restrict__ wvb,
    unsigned short* __restrict__ Qt, unsigned short* __restrict__ Kt,
    unsigned short* __restrict__ Vf) {
  __shared__ unsigned short xT[64][264];        // [token][c], +8 pad
  const int tid = threadIdx.x;
  const int n0 = blockIdx.x * 64;
  const int b = blockIdx.y;
  const int z = blockIdx.z;
  const float* xb = x + (size_t)b * Cn * Nn;
  {
    int cbase = tid >> 4;
    int nn = (tid & 15) * 4;
#pragma unroll
    for (int it = 0; it < 16; ++it) {
      int c = cbase + 16 * it;
      float4 v = *(const float4*)(xb + (size_t)c * Nn + n0 + nn);
      xT[nn + 0][c] = f2h(v.x);
      xT[nn + 1][c] = f2h(v.y);
      xT[nn + 2][c] = f2h(v.z);
      xT[nn + 3][c] = f2h(v.w);
    }
  }
  __syncthreads();
  const int lane = tid & 63, w = tid >> 6;
  const int i = lane & 15, g = lane >> 4;
  f16x8 xf[8];                                  // x^T frags
#pragma unroll
  for (int ks = 0; ks < 8; ++ks)
    xf[ks] = *(const f16x8*)(&xT[w * 16 + i][32 * ks + 8 * g]);

  if (z < 2) {                                  // Q or K -> token-major [N][C]
    const unsigned short* wm = z ? wkb : wqb;
    unsigned short* op = z ? Kt : Qt;
    const size_t tokbase = (size_t)b * Nn + n0 + w * 16;
    for (int ot = 0; ot < 16; ++ot) {
      f32x4 acc = {0.f, 0.f, 0.f, 0.f};
      const unsigned short* wr = wm + (ot * 16 + i) * Cn + 8 * g;
#pragma unroll
      for (int ks = 0; ks < 8; ++ks)
        acc = MFMA16(xf[ks], *(const f16x8*)(wr + 32 * ks), acc);
#pragma unroll
      for (int r = 0; r < 4; ++r)
        op[(tokbase + 4 * g + r) * Cn + ot * 16 + i] = f2h(acc[r]);
    }
  } else {                                      // V -> feature-major [C][N]
    for (int ot = 0; ot < 16; ++ot) {
      f32x4 acc = {0.f, 0.f, 0.f, 0.f};
      const unsigned short* wr = wvb + (ot * 16 + i) * Cn + 8 * g;
#pragma unroll
      for (int ks = 0; ks < 8; ++ks)
        acc = MFMA16(*(const f16x8*)(wr + 32 * ks), xf[ks], acc);
#pragma unroll
      for (int r = 0; r < 4; ++r)
        Vf[((size_t)b * Cn + ot * 16 + 4 * g + r) * Nn + n0 + w * 16 + i] = f2h(acc[r]);
    }
  }
}

// ---------------- flash attention, split-K, 32x32 MFMA ----------------
// grid Bn*splits*18, 256 thr = 4 waves x 32 queries. 32-key chunks.
// Swapped S = mfma32(Kfrag, Qfrag): D[key][query], lane: query=l&31,
// keys kappa(r,hi) = (r&3)+8*(r>>2)+4*hi (hi=l>>5), r=0..15.
// A/B frag (32x32x16): row/col = l&31, k = 8*hi + j (8 contiguous).
// PV: O^T[c][query] = mfma32(Vt_frag, P_frag): A=V^T[c][key], B=P[key][query].
__global__ __launch_bounds__(256, 2) void attn_split(
    const unsigned short* __restrict__ Qt, const unsigned short* __restrict__ Kt,
    const unsigned short* __restrict__ Vf,
    float* __restrict__ P, float* __restrict__ ml, int splits) {
  const int nblk = gridDim.x;                   // divisible by 8
  const int cpx = nblk >> 3;
  const int swz = (blockIdx.x & 7) * cpx + (blockIdx.x >> 3);  // XCD chunked
  const int per_b = splits * 18;
  const int b = swz / per_b;
  const int rem = swz - b * per_b;
  const int s = rem / 18;
  const int qt = rem - s * 18;
  const int n0 = qt * 128;
  const int kn = Nn / splits, k0 = s * kn;

  const int tid = threadIdx.x, lane = tid & 63, w = tid >> 6;
  const int q = lane & 31, hi = lane >> 5;
  const int q0 = n0 + w * 32;

  // resident Q B-frags: Q[c][query]: lane: query=q, c = 16*ks + 8*hi + j
  const unsigned short* Qb = Qt + ((size_t)b * Nn + q0 + q) * Cn + 8 * hi;
  f16x8 qf[16];
#pragma unroll
  for (int ks = 0; ks < 16; ++ks) qf[ks] = *(const f16x8*)(Qb + 16 * ks);

  f32x16 acc[8];
#pragma unroll
  for (int ct = 0; ct < 8; ++ct) acc[ct] = (f32x16)(0.f);
  float m = -1e30f, lsum = 0.f;

  const unsigned short* Kb = Kt + (size_t)b * Nn * Cn + (size_t)q * Cn + 8 * hi;
  const unsigned short* Vb = Vf + (size_t)b * Cn * Nn + (size_t)q * Nn + 8 * hi;

  for (int jc = 0; jc < kn; jc += 32) {
    // ---- QK^T: d[key][query], 16 chained MFMAs over c=256 ----
    const unsigned short* kp = Kb + (size_t)(k0 + jc) * Cn;
    f32x16 d = (f32x16)(0.f);
#pragma unroll
    for (int ks = 0; ks < 16; ++ks)
      d = MFMA32(*(const f16x8*)(kp + 16 * ks), qf[ks], d);

    // ---- online softmax: lane owns query q, 16 scores ----
    float mx = d[0];
#pragma unroll
    for (int r = 1; r < 16; ++r) mx = fmaxf(mx, d[r]);
    mx = fmaxf(mx, __shfl_xor(mx, 32));         // full 32-key max
    if (__any(mx > m + 8.f)) {                  // defer-max (THR=8)
      float mnew = fmaxf(m, mx);
      float alpha = __expf(m - mnew);
      m = mnew;
      lsum *= alpha;
#pragma unroll
      for (int ct = 0; ct < 8; ++ct)
#pragma unroll
        for (int r = 0; r < 16; ++r) acc[ct][r] *= alpha;
    }
    float p[16];
#pragma unroll
    for (int r = 0; r < 16; ++r) p[r] = __expf(d[r] - m);
    float cs = 0.f;
#pragma unroll
    for (int r = 0; r < 16; ++r) cs += p[r];
    cs += __shfl_xor(cs, 32);
    lsum += cs;

    // ---- P -> B-frags (keys 0..15 | 16..31), half-wave exchange ----
    // own keys: hi=0: {0-3,8-11,16-19,24-27}; hi=1: +4.
    unsigned A0 = pk2(p[0], p[1]), A1 = pk2(p[2], p[3]);
    unsigned A2 = pk2(p[4], p[5]), A3 = pk2(p[6], p[7]);
    unsigned A4 = pk2(p[8], p[9]), A5 = pk2(p[10], p[11]);
    unsigned A6 = pk2(p[12], p[13]), A7 = pk2(p[14], p[15]);
    unsigned s0 = __shfl_xor(A0, 32), s1 = __shfl_xor(A1, 32);
    unsigned s2 = __shfl_xor(A2, 32), s3 = __shfl_xor(A3, 32);
    unsigned s4 = __shfl_xor(A4, 32), s5 = __shfl_xor(A5, 32);
    unsigned s6 = __shfl_xor(A6, 32), s7 = __shfl_xor(A7, 32);
    union { unsigned u[4]; f16x8 v; } pb0, pb1;
    pb0.u[0] = hi ? s2 : A0;  pb0.u[1] = hi ? s3 : A1;   // j=0..3: keys 16*0+8hi+j
    pb0.u[2] = hi ? A2 : s0;  pb0.u[3] = hi ? A3 : s1;   // j=4..7
    pb1.u[0] = hi ? s6 : A4;  pb1.u[1] = hi ? s7 : A5;
    pb1.u[2] = hi ? A6 : s4;  pb1.u[3] = hi ? A7 : s5;

    // ---- PV: acc[ct] over c-tiles, A = V^T[c][key] ----
    const unsigned short* vp = Vb + k0 + jc;
#pragma unroll
    for (int ct = 0; ct < 8; ++ct) {
      acc[ct] = MFMA32(*(const f16x8*)(vp + (size_t)ct * 32 * Nn), pb0.v, acc[ct]);
      acc[ct] = MFMA32(*(const f16x8*)(vp + (size_t)ct * 32 * Nn + 16), pb1.v, acc[ct]);
    }
  }

  // ---- epilogue: raw partials, c-major; c = 32ct + (r&3)+8*(r>>2)+4hi ----
  float* Pb = P + (size_t)(s * Bn + b) * Cn * Nn;
#pragma unroll
  for (int ct = 0; ct < 8; ++ct)
#pragma unroll
    for (int r = 0; r < 16; ++r) {
      int c = 32 * ct + (r & 3) + 8 * (r >> 2) + 4 * hi;
      Pb[(size_t)c * Nn + q0 + q] = acc[ct][r];
    }
  if (!hi)
    *(float2*)&ml[((size_t)(s * Bn + b) * Nn + q0 + q) * 2] = make_float2(m, lsum);
}

// ---------------- combine partials + normalize + residual ----------------
// grid Bn*Nn/32, 256 thr. Block: (b, 32-n tile) x all 256 c.
__global__ __launch_bounds__(256) void combine_k(
    const float* __restrict__ x, const float* __restrict__ P,
    const float* __restrict__ ml, float* __restrict__ out, int splits) {
  __shared__ float sc[4][32];
  const int tpb = Nn / 32;                      // 72
  const int b = blockIdx.x / tpb;
  const int n0 = (blockIdx.x - b * tpb) * 32;
  const int t = threadIdx.x;
  if (t < 32) {
    const int n = n0 + t;
    const size_t sstr = (size_t)Bn * Nn * 2;
    const float* mlb = ml + ((size_t)b * Nn + n) * 2;
    float m0 = mlb[0], l0 = mlb[1];
    float m1 = -1e30f, l1 = 0.f, m2 = -1e30f, l2 = 0.f, m3 = -1e30f, l3 = 0.f;
    if (splits > 1) { m1 = mlb[sstr]; l1 = mlb[sstr + 1]; }
    if (splits > 2) { m2 = mlb[2 * sstr]; l2 = mlb[2 * sstr + 1]; }
    if (splits > 3) { m3 = mlb[3 * sstr]; l3 = mlb[3 * sstr + 1]; }
    float M = fmaxf(fmaxf(m0, m1), fmaxf(m2, m3));
    float f0 = __expf(m0 - M), f1 = __expf(m1 - M);
    float f2 = __expf(m2 - M), f3 = __expf(m3 - M);
    float rden = 1.f / (f0 * l0 + f1 * l1 + f2 * l2 + f3 * l3);
    sc[0][t] = f0 * rden; sc[1][t] = f1 * rden;
    sc[2][t] = f2 * rden; sc[3][t] = f3 * rden;
  }
  __syncthreads();
  const int nl4 = (t & 7) * 4, c0 = t >> 3;
  const size_t pstr = (size_t)Bn * Cn * Nn;
  const float* xb = x + (size_t)b * Cn * Nn;
  float* ob = out + (size_t)b * Cn * Nn;
#pragma unroll
  for (int k = 0; k < 8; ++k) {
    const int c = c0 + 32 * k;
    const float* Pp = P + ((size_t)b * Cn + c) * Nn + n0 + nl4;
    f32x4 a = {0.f, 0.f, 0.f, 0.f};
    for (int s2 = 0; s2 < splits; ++s2) {
      f32x4 p = *(const f32x4*)(Pp + s2 * pstr);
      f32x4 sv = *(const f32x4*)&sc[s2][nl4];
      a += sv * p;
    }
    f32x4 xv = *(const f32x4*)(xb + (size_t)c * Nn + n0 + nl4);
    *(f32x4*)(ob + (size_t)c * Nn + n0 + nl4) = xv + a;
  }
}

// ---------------- fallback: self-contained attention (ws too small) --------
__global__ __launch_bounds__(256) void attn_kernel(
    const float* __restrict__ x, const unsigned short* __restrict__ Qt,
    const unsigned short* __restrict__ Kt, const unsigned short* __restrict__ Vf,
    float* __restrict__ out) {
  __shared__ float OT[128][65];
  int bid = (blockIdx.x & 7) * 36 + (blockIdx.x >> 3);
  const int b = bid / 36, qt = bid - 36 * b;
  const int n0 = qt * 64;
  const int tid = threadIdx.x, lane = tid & 63, w = tid >> 6;
  const int i = lane & 15, g = lane >> 4;
  const int iw = n0 + w * 16;
  const unsigned short* Qb = Qt + ((size_t)b * Nn + iw + i) * Cn + 8 * g;
  f16x8 qf[8];
#pragma unroll
  for (int ks = 0; ks < 8; ++ks) qf[ks] = *(const f16x8*)(Qb + 32 * ks);
  f32x4 acc[16];
#pragma unroll
  for (int ct = 0; ct < 16; ++ct) acc[ct] = (f32x4){0.f, 0.f, 0.f, 0.f};
  float m = -1e30f, lsum = 0.f;
  const unsigned short* Kb = Kt + (size_t)b * Nn * Cn + i * Cn + 8 * g;
  const unsigned short* Vb = Vf + (size_t)b * Cn * Nn + (size_t)i * Nn + 8 * g;
  for (int j0 = 0; j0 < Nn; j0 += 32) {
    const unsigned short* kp = Kb + (size_t)j0 * Cn;
    f32x4 d0 = {0.f, 0.f, 0.f, 0.f}, d1 = {0.f, 0.f, 0.f, 0.f};
#pragma unroll
    for (int ks = 0; ks < 8; ++ks) {
      d0 = MFMA16(*(const f16x8*)(kp + 32 * ks), qf[ks], d0);
      d1 = MFMA16(*(const f16x8*)(kp + 16 * Cn + 32 * ks), qf[ks], d1);
    }
    float mx = fmaxf(fmaxf(fmaxf(d0[0], d0[1]), fmaxf(d0[2], d0[3])),
                     fmaxf(fmaxf(d1[0], d1[1]), fmaxf(d1[2], d1[3])));
    mx = fmaxf(mx, __shfl_xor(mx, 16));
    mx = fmaxf(mx, __shfl_xor(mx, 32));
    if (__any(mx > m + 8.f)) {
      float mnew = fmaxf(m, mx);
      float alpha = __expf(m - mnew);
      m = mnew;
      float ar0 = __shfl(alpha, 4 * g + 0), ar1 = __shfl(alpha, 4 * g + 1);
      float ar2 = __shfl(alpha, 4 * g + 2), ar3 = __shfl(alpha, 4 * g + 3);
      lsum *= alpha;
#pragma unroll
      for (int ct = 0; ct < 16; ++ct) {
        acc[ct][0] *= ar0; acc[ct][1] *= ar1; acc[ct][2] *= ar2; acc[ct][3] *= ar3;
      }
    }
    float p0[4], p1[4];
#pragma unroll
    for (int r = 0; r < 4; ++r) {
      p0[r] = __expf(d0[r] - m);
      p1[r] = __expf(d1[r] - m);
    }
    float cs = (p0[0] + p0[1]) + (p0[2] + p0[3]) + (p1[0] + p1[1]) + (p1[2] + p1[3]);
    cs += __shfl_xor(cs, 16);
    cs += __shfl_xor(cs, 32);
    lsum += cs;
    const int srcA = i + 16 * ((2 * g) & 3);
    const int srcB = i + 16 * ((2 * g + 1) & 3);
    union { unsigned short u[8]; f16x8 v; } pu;
#pragma unroll
    for (int r = 0; r < 4; ++r) {
      float a0s = __shfl(p0[r], srcA);
      float a1s = __shfl(p1[r], srcA);
      float b0s = __shfl(p0[r], srcB);
      float b1s = __shfl(p1[r], srcB);
      pu.u[r] = f2h(g < 2 ? a0s : a1s);
      pu.u[4 + r] = f2h(g < 2 ? b0s : b1s);
    }
    f16x8 pf = pu.v;
    const unsigned short* vp = Vb + j0;
#pragma unroll
    for (int ct = 0; ct < 16; ++ct)
      acc[ct] = MFMA16(pf, *(const f16x8*)(vp + (size_t)ct * 16 * Nn), acc[ct]);
  }
  float l0 = __shfl(lsum, 4 * g + 0), l1 = __shfl(lsum, 4 * g + 1);
  float l2 = __shfl(lsum, 4 * g + 2), l3 = __shfl(lsum, 4 * g + 3);
  f32x4 rl = {1.f / l0, 1.f / l1, 1.f / l2, 1.f / l3};
  const float* xb = x + (size_t)b * Cn * Nn;
  float* ob = out + (size_t)b * Cn * Nn;
#pragma unroll 1
  for (int h = 0; h < 2; ++h) {
    if (h) __syncthreads();
#pragma unroll
    for (int ctl = 0; ctl < 8; ++ctl) {
      int ct = 8 * h + ctl;
#pragma unroll
      for (int r = 0; r < 4; ++r)
        OT[ctl * 16 + i][w * 16 + 4 * g + r] = acc[ct][r] * rl[r];
    }
    __syncthreads();
    int c0 = w * 32;
    for (int cc = 0; cc < 32; ++cc) {
      int c = 128 * h + c0 + cc;
      size_t idx = (size_t)c * Nn + n0 + lane;
      ob[idx] = xb[idx] + OT[c0 + cc][lane];
    }
  }
}

extern "C" void kernel_launch(void* const* d_in, const int* in_sizes, int n_in,
                              void* d_out, int out_size, void* d_ws, size_t ws_size,
                              hipStream_t stream) {
  const float* x = (const float*)d_in[0];
  const float* wq = (const float*)d_in[1];
  const float* wk = (const float*)d_in[2];
  const float* wv = (const float*)d_in[3];
  float* out = (float*)d_out;

  unsigned short* wqb = (unsigned short*)d_ws;
  unsigned short* wkb = wqb + Cn * Cn;
  unsigned short* wvb = wkb + Cn * Cn;
  unsigned short* Qt = wvb + Cn * Cn;
  unsigned short* Kt = Qt + (size_t)Bn * Nn * Cn;
  unsigned short* Vf = Kt + (size_t)Bn * Nn * Cn;
  const size_t baseB = (size_t)(3 * Cn * Cn + 3 * (size_t)Bn * Nn * Cn) * 2;
  const size_t perSplitB = (size_t)Bn * Nn * Cn * 4 + (size_t)Bn * Nn * 2 * 4;

  int splits = 0;
  if (baseB + 4 * perSplitB <= ws_size) splits = 4;
  else if (baseB + 2 * perSplitB <= ws_size) splits = 2;
  else if (baseB + 1 * perSplitB <= ws_size) splits = 1;

  hipLaunchKernelGGL(cvt_w, dim3(3 * Cn * Cn / 256), dim3(256), 0, stream, wq, wk, wv, wqb);
  hipLaunchKernelGGL(qkv_proj, dim3(Nn / 64, Bn, 3), dim3(256), 0, stream,
                     x, wqb, wkb, wvb, Qt, Kt, Vf);
  if (splits) {
    float* P = (float*)((unsigned short*)d_ws + 3 * Cn * Cn + 3 * (size_t)Bn * Nn * Cn);
    float* ml = P + (size_t)splits * Bn * Nn * Cn;
    hipLaunchKernelGGL(attn_split, dim3(Bn * splits * 18), dim3(256), 0, stream,
                       Qt, Kt, Vf, P, ml, splits);
    hipLaunchKernelGGL(combine_k, dim3(Bn * Nn / 32), dim3(256), 0, stream,
                       x, P, ml, out, splits);
  } else {
    hipLaunchKernelGGL(attn_kernel, dim3(Bn * Nn / 64), dim3(256), 0, stream,
                       x, Qt, Kt, Vf, out);
  }
}

// Round 6
// 231.718 us; speedup vs baseline: 2.6572x; 1.3259x over previous
//
#include <hip/hip_runtime.h>
#include <hip/hip_bf16.h>

// SelfAttention: x[8,256,48,48] fp32; wq/wk/wv[256,256] fp32.
// out = x + attn(softmax(q^T k), v). B=8, C=256, N=2304. fp16 MFMA path.
//
// R5: attn_split loads were 512B/4608B-strided GATHERS (64 cachelines per
// 16B-lane load instr) -> ~29k cy per 32-key chunk. MfmaUtil 7.8%.
// R6 fix: LDS-stage K (token-major [32][256]) + V (feature-major [256][32])
// per block via global_load_lds w=16 (coalesced), double-buffered, 2-phase
// schedule. XOR-swizzled (linear LDS dest + inv-swizzled global source +
// swizzled ds_read; K: ^((key&7)<<4), V: ^(((c>>1)&3)<<4) -> 4-way residual).
//
// ws layout: wq_h/wk_h/wv_h [65536 each, fp16]; Qt,Kt [B*N*C fp16 token-major];
// Vf [B*C*N fp16 feature-major]; P [splits][B][C][N] f32; ml [splits][B][N][2] f32.

#define DEVI __device__ __forceinline__

typedef _Float16 f16x8 __attribute__((ext_vector_type(8)));
typedef float f32x4 __attribute__((ext_vector_type(4)));
typedef float f32x16 __attribute__((ext_vector_type(16)));

constexpr int Bn = 8, Cn = 256, Nn = 48 * 48;   // 2304

DEVI unsigned short f2h(float f) {              // fp32 -> fp16 (RNE)
  _Float16 h = (_Float16)f;
  return __builtin_bit_cast(unsigned short, h);
}
DEVI unsigned pk2(float a, float b) {           // pack 2 f32 -> f16x2 (RTZ)
  auto h = __builtin_amdgcn_cvt_pkrtz(a, b);
  return __builtin_bit_cast(unsigned, h);
}
DEVI void stage16(const unsigned short* g, unsigned short* l) {
  __builtin_amdgcn_global_load_lds(
      (const __attribute__((address_space(1))) void*)g,
      (__attribute__((address_space(3))) void*)l, 16, 0, 0);
}

#define MFMA16(a, b, c) __builtin_amdgcn_mfma_f32_16x16x32_f16((a), (b), (c), 0, 0, 0)
#define MFMA32(a, b, c) __builtin_amdgcn_mfma_f32_32x32x16_f16((a), (b), (c), 0, 0, 0)

__global__ __launch_bounds__(256) void cvt_w(const float* __restrict__ wq,
                                             const float* __restrict__ wk,
                                             const float* __restrict__ wv,
                                             unsigned short* __restrict__ o) {
  int idx = blockIdx.x * 256 + threadIdx.x;     // 3*65536 total
  const float* s = (idx < Cn * Cn) ? wq : (idx < 2 * Cn * Cn) ? wk : wv;
  o[idx] = f2h(s[idx & (Cn * Cn - 1)]);
}

// ---------------- QKV projection ----------------
// grid (N/64, B, 3), 256 thr (4 waves, 16 tokens each). z: 0=Q 1=K 2=V.
// 16x16x32 frags: A/B lane l: row/col=l&15, k=8*(l>>4)+j. C/D: col=l&15, row=4*(l>>4)+r.
__global__ __launch_bounds__(256) void qkv_proj(
    const float* __restrict__ x,
    const unsigned short* __restrict__ wqb, const unsigned short* __restrict__ wkb,
    const unsigned short* __restrict__ wvb,
    unsigned short* __restrict__ Qt, unsigned short* __restrict__ Kt,
    unsigned short* __restrict__ Vf) {
  __shared__ unsigned short xT[64][264];        // [token][c], +8 pad
  const int tid = threadIdx.x;
  const int n0 = blockIdx.x * 64;
  const int b = blockIdx.y;
  const int z = blockIdx.z;
  const float* xb = x + (size_t)b * Cn * Nn;
  {
    int cbase = tid >> 4;
    int nn = (tid & 15) * 4;
#pragma unroll
    for (int it = 0; it < 16; ++it) {
      int c = cbase + 16 * it;
      float4 v = *(const float4*)(xb + (size_t)c * Nn + n0 + nn);
      xT[nn + 0][c] = f2h(v.x);
      xT[nn + 1][c] = f2h(v.y);
      xT[nn + 2][c] = f2h(v.z);
      xT[nn + 3][c] = f2h(v.w);
    }
  }
  __syncthreads();
  const int lane = tid & 63, w = tid >> 6;
  const int i = lane & 15, g = lane >> 4;
  f16x8 xf[8];                                  // x^T frags
#pragma unroll
  for (int ks = 0; ks < 8; ++ks)
    xf[ks] = *(const f16x8*)(&xT[w * 16 + i][32 * ks + 8 * g]);

  if (z < 2) {                                  // Q or K -> token-major [N][C]
    const unsigned short* wm = z ? wkb : wqb;
    unsigned short* op = z ? Kt : Qt;
    const size_t tokbase = (size_t)b * Nn + n0 + w * 16;
    for (int ot = 0; ot < 16; ++ot) {
      f32x4 acc = {0.f, 0.f, 0.f, 0.f};
      const unsigned short* wr = wm + (ot * 16 + i) * Cn + 8 * g;
#pragma unroll
      for (int ks = 0; ks < 8; ++ks)
        acc = MFMA16(xf[ks], *(const f16x8*)(wr + 32 * ks), acc);
#pragma unroll
      for (int r = 0; r < 4; ++r)
        op[(tokbase + 4 * g + r) * Cn + ot * 16 + i] = f2h(acc[r]);
    }
  } else {                                      // V -> feature-major [C][N]
    for (int ot = 0; ot < 16; ++ot) {
      f32x4 acc = {0.f, 0.f, 0.f, 0.f};
      const unsigned short* wr = wvb + (ot * 16 + i) * Cn + 8 * g;
#pragma unroll
      for (int ks = 0; ks < 8; ++ks)
        acc = MFMA16(*(const f16x8*)(wr + 32 * ks), xf[ks], acc);
#pragma unroll
      for (int r = 0; r < 4; ++r)
        Vf[((size_t)b * Cn + ot * 16 + 4 * g + r) * Nn + n0 + w * 16 + i] = f2h(acc[r]);
    }
  }
}

// ---------------- flash attention, split-K, LDS-staged, 32x32 MFMA ---------
// grid Bn*splits*18, 256 thr = 4 waves x 32 queries. 32-key chunks.
// LDS per buf: Ks[32 key][256 c] fp16 (16KB) + Vs[256 c][32 key] fp16 (16KB).
// Swapped S = mfma32(Kfrag, Qfrag): lane query=l&31, keys (r&3)+8(r>>2)+4hi.
__global__ __launch_bounds__(256, 2) void attn_split(
    const unsigned short* __restrict__ Qt, const unsigned short* __restrict__ Kt,
    const unsigned short* __restrict__ Vf,
    float* __restrict__ P, float* __restrict__ ml, int splits) {
  __shared__ unsigned short smem[32768];        // 64 KB: [buf][K 8192 | V 8192]
  const int nblk = gridDim.x;                   // divisible by 8
  const int cpx = nblk >> 3;
  const int swz = (blockIdx.x & 7) * cpx + (blockIdx.x >> 3);  // XCD chunked
  const int per_b = splits * 18;
  const int b = swz / per_b;
  const int rem = swz - b * per_b;
  const int s = rem / 18;
  const int qt = rem - s * 18;
  const int n0 = qt * 128;
  const int kn = Nn / splits, k0 = s * kn;
  const int NT = kn / 32;

  const int tid = threadIdx.x, lane = tid & 63, w = tid >> 6;
  const int q = lane & 31, hi = lane >> 5;
  const int q0 = n0 + w * 32;

  const unsigned short* Kt_b = Kt + (size_t)b * Nn * Cn;
  const unsigned short* Vf_b = Vf + (size_t)b * Cn * Nn;

  // ---- stage chunk j0 into buf (K: inv-swz ^((key&7)<<4); V: ^(((c>>1)&3)<<4))
  auto stage_chunk = [&](int j0, unsigned short* buf) {
    unsigned short* Ks = buf;
    unsigned short* Vs = buf + 8192;
#pragma unroll
    for (int sc = 0; sc < 4; ++sc) {
      int L = sc * 4096 + tid * 16;             // byte offset in Ks
      int key = L >> 9;
      int cb = (L ^ ((key & 7) << 4)) & 511;
      stage16(Kt_b + (size_t)(j0 + key) * Cn + (cb >> 1),
              Ks + (sc * 4096 + w * 1024) / 2);
    }
#pragma unroll
    for (int sc = 0; sc < 4; ++sc) {
      int L = sc * 4096 + tid * 16;             // byte offset in Vs
      int c = L >> 6;
      int kb = (L ^ (((c >> 1) & 3) << 4)) & 63;
      stage16(Vf_b + (size_t)c * Nn + j0 + (kb >> 1),
              Vs + (sc * 4096 + w * 1024) / 2);
    }
  };

  stage_chunk(k0, smem);                        // prologue: buf0

  // resident Q B-frags: lane: query=q, c = 16*ks + 8*hi + j (overlaps staging)
  const unsigned short* Qb = Qt + ((size_t)b * Nn + q0 + q) * Cn + 8 * hi;
  f16x8 qf[16];
#pragma unroll
  for (int ks = 0; ks < 16; ++ks) qf[ks] = *(const f16x8*)(Qb + 16 * ks);

  f32x16 acc[8];
#pragma unroll
  for (int ct = 0; ct < 8; ++ct) acc[ct] = (f32x16)(0.f);
  float m = -1e30f, lsum = 0.f;

  const int xq = (q & 7) << 4;                  // K read swizzle
  const int xv = ((q >> 1) & 3) << 4;           // V read swizzle (row c: c&31==q? no: per-read c uses lane l&31 = q)

  __syncthreads();                              // buf0 ready (drains vmcnt)

  for (int t = 0; t < NT; ++t) {
    const int cur = t & 1;
    if (t + 1 < NT) stage_chunk(k0 + (t + 1) * 32, smem + (cur ^ 1) * 16384);

    const char* KsB = (const char*)(smem + cur * 16384);
    const char* VsB = (const char*)(smem + cur * 16384 + 8192);

    // ---- QK^T: d[key][query], 16 chained MFMAs over c=256 ----
    f32x16 d = (f32x16)(0.f);
#pragma unroll
    for (int ks = 0; ks < 16; ++ks) {
      f16x8 kf = *(const f16x8*)(KsB + ((q * 512 + 32 * ks + 16 * hi) ^ xq));
      d = MFMA32(kf, qf[ks], d);
    }

    // ---- online softmax: lane owns query q, 16 scores ----
    float mx = d[0];
#pragma unroll
    for (int r = 1; r < 16; ++r) mx = fmaxf(mx, d[r]);
    mx = fmaxf(mx, __shfl_xor(mx, 32));         // full 32-key max
    if (__any(mx > m + 8.f)) {                  // defer-max (THR=8)
      float mnew = fmaxf(m, mx);
      float alpha = __expf(m - mnew);
      m = mnew;
      lsum *= alpha;
#pragma unroll
      for (int ct = 0; ct < 8; ++ct)
#pragma unroll
        for (int r = 0; r < 16; ++r) acc[ct][r] *= alpha;
    }
    float p[16];
#pragma unroll
    for (int r = 0; r < 16; ++r) p[r] = __expf(d[r] - m);
    float cs = 0.f;
#pragma unroll
    for (int r = 0; r < 16; ++r) cs += p[r];
    cs += __shfl_xor(cs, 32);
    lsum += cs;

    // ---- P -> B-frags (keys 0..15 | 16..31), half-wave exchange ----
    unsigned A0 = pk2(p[0], p[1]), A1 = pk2(p[2], p[3]);
    unsigned A2 = pk2(p[4], p[5]), A3 = pk2(p[6], p[7]);
    unsigned A4 = pk2(p[8], p[9]), A5 = pk2(p[10], p[11]);
    unsigned A6 = pk2(p[12], p[13]), A7 = pk2(p[14], p[15]);
    unsigned s0 = __shfl_xor(A0, 32), s1 = __shfl_xor(A1, 32);
    unsigned s2 = __shfl_xor(A2, 32), s3 = __shfl_xor(A3, 32);
    unsigned s4 = __shfl_xor(A4, 32), s5 = __shfl_xor(A5, 32);
    unsigned s6 = __shfl_xor(A6, 32), s7 = __shfl_xor(A7, 32);
    union { unsigned u[4]; f16x8 v; } pb0, pb1;
    pb0.u[0] = hi ? s2 : A0;  pb0.u[1] = hi ? s3 : A1;
    pb0.u[2] = hi ? A2 : s0;  pb0.u[3] = hi ? A3 : s1;
    pb1.u[0] = hi ? s6 : A4;  pb1.u[1] = hi ? s7 : A5;
    pb1.u[2] = hi ? A6 : s4;  pb1.u[3] = hi ? A7 : s5;

    // ---- PV: acc[ct] over 8 c-tiles; A = V^T[c = 32ct+q][keys] from LDS ----
#pragma unroll
    for (int ct = 0; ct < 8; ++ct) {
      f16x8 v0 = *(const f16x8*)(VsB + (((32 * ct + q) * 64 + 16 * hi) ^ xv));
      f16x8 v1 = *(const f16x8*)(VsB + (((32 * ct + q) * 64 + 32 + 16 * hi) ^ xv));
      acc[ct] = MFMA32(v0, pb0.v, acc[ct]);
      acc[ct] = MFMA32(v1, pb1.v, acc[ct]);
    }
    __syncthreads();                            // drains next-buf stage loads
  }

  // ---- epilogue: raw partials, c-major; c = 32ct + (r&3)+8*(r>>2)+4hi ----
  float* Pb = P + (size_t)(s * Bn + b) * Cn * Nn;
#pragma unroll
  for (int ct = 0; ct < 8; ++ct)
#pragma unroll
    for (int r = 0; r < 16; ++r) {
      int c = 32 * ct + (r & 3) + 8 * (r >> 2) + 4 * hi;
      Pb[(size_t)c * Nn + q0 + q] = acc[ct][r];
    }
  if (!hi)
    *(float2*)&ml[((size_t)(s * Bn + b) * Nn + q0 + q) * 2] = make_float2(m, lsum);
}

// ---------------- combine partials + normalize + residual ----------------
// grid Bn*Nn/32, 256 thr. Block: (b, 32-n tile) x all 256 c.
__global__ __launch_bounds__(256) void combine_k(
    const float* __restrict__ x, const float* __restrict__ P,
    const float* __restrict__ ml, float* __restrict__ out, int splits) {
  __shared__ float sc[4][32];
  const int tpb = Nn / 32;                      // 72
  const int b = blockIdx.x / tpb;
  const int n0 = (blockIdx.x - b * tpb) * 32;
  const int t = threadIdx.x;
  if (t < 32) {
    const int n = n0 + t;
    const size_t sstr = (size_t)Bn * Nn * 2;
    const float* mlb = ml + ((size_t)b * Nn + n) * 2;
    float m0 = mlb[0], l0 = mlb[1];
    float m1 = -1e30f, l1 = 0.f, m2 = -1e30f, l2 = 0.f, m3 = -1e30f, l3 = 0.f;
    if (splits > 1) { m1 = mlb[sstr]; l1 = mlb[sstr + 1]; }
    if (splits > 2) { m2 = mlb[2 * sstr]; l2 = mlb[2 * sstr + 1]; }
    if (splits > 3) { m3 = mlb[3 * sstr]; l3 = mlb[3 * sstr + 1]; }
    float M = fmaxf(fmaxf(m0, m1), fmaxf(m2, m3));
    float f0 = __expf(m0 - M), f1 = __expf(m1 - M);
    float f2 = __expf(m2 - M), f3 = __expf(m3 - M);
    float rden = 1.f / (f0 * l0 + f1 * l1 + f2 * l2 + f3 * l3);
    sc[0][t] = f0 * rden; sc[1][t] = f1 * rden;
    sc[2][t] = f2 * rden; sc[3][t] = f3 * rden;
  }
  __syncthreads();
  const int nl4 = (t & 7) * 4, c0 = t >> 3;
  const size_t pstr = (size_t)Bn * Cn * Nn;
  const float* xb = x + (size_t)b * Cn * Nn;
  float* ob = out + (size_t)b * Cn * Nn;
#pragma unroll
  for (int k = 0; k < 8; ++k) {
    const int c = c0 + 32 * k;
    const float* Pp = P + ((size_t)b * Cn + c) * Nn + n0 + nl4;
    f32x4 a = {0.f, 0.f, 0.f, 0.f};
    for (int s2 = 0; s2 < splits; ++s2) {
      f32x4 p = *(const f32x4*)(Pp + s2 * pstr);
      f32x4 sv = *(const f32x4*)&sc[s2][nl4];
      a += sv * p;
    }
    f32x4 xv = *(const f32x4*)(xb + (size_t)c * Nn + n0 + nl4);
    *(f32x4*)(ob + (size_t)c * Nn + n0 + nl4) = xv + a;
  }
}

// ---------------- fallback: self-contained attention (ws too small) --------
__global__ __launch_bounds__(256) void attn_kernel(
    const float* __restrict__ x, const unsigned short* __restrict__ Qt,
    const unsigned short* __restrict__ Kt, const unsigned short* __restrict__ Vf,
    float* __restrict__ out) {
  __shared__ float OT[128][65];
  int bid = (blockIdx.x & 7) * 36 + (blockIdx.x >> 3);
  const int b = bid / 36, qt = bid - 36 * b;
  const int n0 = qt * 64;
  const int tid = threadIdx.x, lane = tid & 63, w = tid >> 6;
  const int i = lane & 15, g = lane >> 4;
  const int iw = n0 + w * 16;
  const unsigned short* Qb = Qt + ((size_t)b * Nn + iw + i) * Cn + 8 * g;
  f16x8 qf[8];
#pragma unroll
  for (int ks = 0; ks < 8; ++ks) qf[ks] = *(const f16x8*)(Qb + 32 * ks);
  f32x4 acc[16];
#pragma unroll
  for (int ct = 0; ct < 16; ++ct) acc[ct] = (f32x4){0.f, 0.f, 0.f, 0.f};
  float m = -1e30f, lsum = 0.f;
  const unsigned short* Kb = Kt + (size_t)b * Nn * Cn + i * Cn + 8 * g;
  const unsigned short* Vb = Vf + (size_t)b * Cn * Nn + (size_t)i * Nn + 8 * g;
  for (int j0 = 0; j0 < Nn; j0 += 32) {
    const unsigned short* kp = Kb + (size_t)j0 * Cn;
    f32x4 d0 = {0.f, 0.f, 0.f, 0.f}, d1 = {0.f, 0.f, 0.f, 0.f};
#pragma unroll
    for (int ks = 0; ks < 8; ++ks) {
      d0 = MFMA16(*(const f16x8*)(kp + 32 * ks), qf[ks], d0);
      d1 = MFMA16(*(const f16x8*)(kp + 16 * Cn + 32 * ks), qf[ks], d1);
    }
    float mx = fmaxf(fmaxf(fmaxf(d0[0], d0[1]), fmaxf(d0[2], d0[3])),
                     fmaxf(fmaxf(d1[0], d1[1]), fmaxf(d1[2], d1[3])));
    mx = fmaxf(mx, __shfl_xor(mx, 16));
    mx = fmaxf(mx, __shfl_xor(mx, 32));
    if (__any(mx > m + 8.f)) {
      float mnew = fmaxf(m, mx);
      float alpha = __expf(m - mnew);
      m = mnew;
      float ar0 = __shfl(alpha, 4 * g + 0), ar1 = __shfl(alpha, 4 * g + 1);
      float ar2 = __shfl(alpha, 4 * g + 2), ar3 = __shfl(alpha, 4 * g + 3);
      lsum *= alpha;
#pragma unroll
      for (int ct = 0; ct < 16; ++ct) {
        acc[ct][0] *= ar0; acc[ct][1] *= ar1; acc[ct][2] *= ar2; acc[ct][3] *= ar3;
      }
    }
    float p0[4], p1[4];
#pragma unroll
    for (int r = 0; r < 4; ++r) {
      p0[r] = __expf(d0[r] - m);
      p1[r] = __expf(d1[r] - m);
    }
    float cs = (p0[0] + p0[1]) + (p0[2] + p0[3]) + (p1[0] + p1[1]) + (p1[2] + p1[3]);
    cs += __shfl_xor(cs, 16);
    cs += __shfl_xor(cs, 32);
    lsum += cs;
    const int srcA = i + 16 * ((2 * g) & 3);
    const int srcB = i + 16 * ((2 * g + 1) & 3);
    union { unsigned short u[8]; f16x8 v; } pu;
#pragma unroll
    for (int r = 0; r < 4; ++r) {
      float a0s = __shfl(p0[r], srcA);
      float a1s = __shfl(p1[r], srcA);
      float b0s = __shfl(p0[r], srcB);
      float b1s = __shfl(p1[r], srcB);
      pu.u[r] = f2h(g < 2 ? a0s : a1s);
      pu.u[4 + r] = f2h(g < 2 ? b0s : b1s);
    }
    f16x8 pf = pu.v;
    const unsigned short* vp = Vb + j0;
#pragma unroll
    for (int ct = 0; ct < 16; ++ct)
      acc[ct] = MFMA16(pf, *(const f16x8*)(vp + (size_t)ct * 16 * Nn), acc[ct]);
  }
  float l0 = __shfl(lsum, 4 * g + 0), l1 = __shfl(lsum, 4 * g + 1);
  float l2 = __shfl(lsum, 4 * g + 2), l3 = __shfl(lsum, 4 * g + 3);
  f32x4 rl = {1.f / l0, 1.f / l1, 1.f / l2, 1.f / l3};
  const float* xb = x + (size_t)b * Cn * Nn;
  float* ob = out + (size_t)b * Cn * Nn;
#pragma unroll 1
  for (int h = 0; h < 2; ++h) {
    if (h) __syncthreads();
#pragma unroll
    for (int ctl = 0; ctl < 8; ++ctl) {
      int ct = 8 * h + ctl;
#pragma unroll
      for (int r = 0; r < 4; ++r)
        OT[ctl * 16 + i][w * 16 + 4 * g + r] = acc[ct][r] * rl[r];
    }
    __syncthreads();
    int c0 = w * 32;
    for (int cc = 0; cc < 32; ++cc) {
      int c = 128 * h + c0 + cc;
      size_t idx = (size_t)c * Nn + n0 + lane;
      ob[idx] = xb[idx] + OT[c0 + cc][lane];
    }
  }
}

extern "C" void kernel_launch(void* const* d_in, const int* in_sizes, int n_in,
                              void* d_out, int out_size, void* d_ws, size_t ws_size,
                              hipStream_t stream) {
  const float* x = (const float*)d_in[0];
  const float* wq = (const float*)d_in[1];
  const float* wk = (const float*)d_in[2];
  const float* wv = (const float*)d_in[3];
  float* out = (float*)d_out;

  unsigned short* wqb = (unsigned short*)d_ws;
  unsigned short* wkb = wqb + Cn * Cn;
  unsigned short* wvb = wkb + Cn * Cn;
  unsigned short* Qt = wvb + Cn * Cn;
  unsigned short* Kt = Qt + (size_t)Bn * Nn * Cn;
  unsigned short* Vf = Kt + (size_t)Bn * Nn * Cn;
  const size_t baseB = (size_t)(3 * Cn * Cn + 3 * (size_t)Bn * Nn * Cn) * 2;
  const size_t perSplitB = (size_t)Bn * Nn * Cn * 4 + (size_t)Bn * Nn * 2 * 4;

  int splits = 0;
  if (baseB + 4 * perSplitB <= ws_size) splits = 4;
  else if (baseB + 2 * perSplitB <= ws_size) splits = 2;
  else if (baseB + 1 * perSplitB <= ws_size) splits = 1;

  hipLaunchKernelGGL(cvt_w, dim3(3 * Cn * Cn / 256), dim3(256), 0, stream, wq, wk, wv, wqb);
  hipLaunchKernelGGL(qkv_proj, dim3(Nn / 64, Bn, 3), dim3(256), 0, stream,
                     x, wqb, wkb, wvb, Qt, Kt, Vf);
  if (splits) {
    float* P = (float*)((unsigned short*)d_ws + 3 * Cn * Cn + 3 * (size_t)Bn * Nn * Cn);
    float* ml = P + (size_t)splits * Bn * Nn * Cn;
    hipLaunchKernelGGL(attn_split, dim3(Bn * splits * 18), dim3(256), 0, stream,
                       Qt, Kt, Vf, P, ml, splits);
    hipLaunchKernelGGL(combine_k, dim3(Bn * Nn / 32), dim3(256), 0, stream,
                       x, P, ml, out, splits);
  } else {
    hipLaunchKernelGGL(attn_kernel, dim3(Bn * Nn / 64), dim3(256), 0, stream,
                       x, Qt, Kt, Vf, out);
  }
}

// Round 7
// 229.653 us; speedup vs baseline: 2.6811x; 1.0090x over previous
//
#include <hip/hip_runtime.h>
#include <hip/hip_bf16.h>

// SelfAttention: x[8,256,48,48] fp32; wq/wk/wv[256,256] fp32.
// out = x + attn(softmax(q^T k), v). B=8, C=256, N=2304. fp16 MFMA path.
//
// R6: LDS-staged attn stalled at 45% summed pipe-busy: 2 waves/SIMD (acc+qf
// ~192 regs) + 2 blocks/CU (64KB LDS) left barrier drains exposed; LDS adds
// a 26us/CU broadcast-redundancy floor. R7: store K/V PRE-SWIZZLED in MFMA
// fragment order (qkv_proj writes them), so attn loads fragments as fully
// contiguous 1KB global loads (L2-resident) straight to registers: no LDS,
// no barriers, no lockstep. P partials stored fp16 normalized per split.
//
// K_swz[kb][ks 16][hi 2][key 32][j 8]: short off = kb*8192+ks*512+hi*256+key*8+j
//   holds K[key of chunk kb][c = 16ks+8hi+j]   (A-frag for QK^T)
// V_swz[kb][ct 8][kh 2][hi 2][c 32][j 8]: off = kb*8192+ct*1024+kh*512+hi*256+c*8+j
//   holds V[c = 32ct+cloc][key = 16kh+8hi+j]   (A-frag = V^T for PV)
// ws: wq/wk/wv fp16 [65536 ea]; Qt [B*N*C] token-major; Ksw,Vsw [B*N*C];
//     P fp16 [splits][B][C][N] (per-split normalized O_s); ml f32 [splits][B][N][2].

#define DEVI __device__ __forceinline__

typedef _Float16 f16x8 __attribute__((ext_vector_type(8)));
typedef float f32x4 __attribute__((ext_vector_type(4)));
typedef float f32x16 __attribute__((ext_vector_type(16)));

constexpr int Bn = 8, Cn = 256, Nn = 48 * 48;   // 2304

DEVI unsigned short f2h(float f) {
  _Float16 h = (_Float16)f;
  return __builtin_bit_cast(unsigned short, h);
}
DEVI float h2f(unsigned short u) {
  return (float)__builtin_bit_cast(_Float16, u);
}
DEVI unsigned pk2(float a, float b) {           // pack 2 f32 -> f16x2 (RTZ)
  auto h = __builtin_amdgcn_cvt_pkrtz(a, b);
  return __builtin_bit_cast(unsigned, h);
}

#define MFMA16(a, b, c) __builtin_amdgcn_mfma_f32_16x16x32_f16((a), (b), (c), 0, 0, 0)
#define MFMA32(a, b, c) __builtin_amdgcn_mfma_f32_32x32x16_f16((a), (b), (c), 0, 0, 0)

__global__ __launch_bounds__(256) void cvt_w(const float* __restrict__ wq,
                                             const float* __restrict__ wk,
                                             const float* __restrict__ wv,
                                             unsigned short* __restrict__ o) {
  int idx = blockIdx.x * 256 + threadIdx.x;     // 3*65536 total
  const float* s = (idx < Cn * Cn) ? wq : (idx < 2 * Cn * Cn) ? wk : wv;
  o[idx] = f2h(s[idx & (Cn * Cn - 1)]);
}

// ---------------- QKV projection ----------------
// grid (N/64, B, 3), 256 thr (4 waves, 16 tokens each). z: 0=Q 1=K 2=V.
// 16x16x32 frags: A/B lane l: row/col=l&15, k=8*(l>>4)+j. C/D: col=l&15, row=4*(l>>4)+r.
__global__ __launch_bounds__(256) void qkv_proj(
    const float* __restrict__ x,
    const unsigned short* __restrict__ wqb, const unsigned short* __restrict__ wkb,
    const unsigned short* __restrict__ wvb,
    unsigned short* __restrict__ Qt, unsigned short* __restrict__ Ksw,
    unsigned short* __restrict__ Vsw) {
  __shared__ unsigned short xT[64][264];        // [token][c], +8 pad
  const int tid = threadIdx.x;
  const int n0 = blockIdx.x * 64;
  const int b = blockIdx.y;
  const int z = blockIdx.z;
  const float* xb = x + (size_t)b * Cn * Nn;
  {
    int cbase = tid >> 4;
    int nn = (tid & 15) * 4;
#pragma unroll
    for (int it = 0; it < 16; ++it) {
      int c = cbase + 16 * it;
      float4 v = *(const float4*)(xb + (size_t)c * Nn + n0 + nn);
      xT[nn + 0][c] = f2h(v.x);
      xT[nn + 1][c] = f2h(v.y);
      xT[nn + 2][c] = f2h(v.z);
      xT[nn + 3][c] = f2h(v.w);
    }
  }
  __syncthreads();
  const int lane = tid & 63, w = tid >> 6;
  const int i = lane & 15, g = lane >> 4;
  f16x8 xf[8];                                  // x^T frags
#pragma unroll
  for (int ks = 0; ks < 8; ++ks)
    xf[ks] = *(const f16x8*)(&xT[w * 16 + i][32 * ks + 8 * g]);

  const int kb0 = (n0 >> 5) + (w >> 1);         // 32-token chunk id
  if (z == 0) {                                 // Q -> token-major [N][C]
    const size_t tokbase = (size_t)b * Nn + n0 + w * 16;
    for (int ot = 0; ot < 16; ++ot) {
      f32x4 acc = {0.f, 0.f, 0.f, 0.f};
      const unsigned short* wr = wqb + (ot * 16 + i) * Cn + 8 * g;
#pragma unroll
      for (int ks = 0; ks < 8; ++ks)
        acc = MFMA16(xf[ks], *(const f16x8*)(wr + 32 * ks), acc);
#pragma unroll
      for (int r = 0; r < 4; ++r)
        Qt[(tokbase + 4 * g + r) * Cn + ot * 16 + i] = f2h(acc[r]);
    }
  } else if (z == 1) {                          // K -> frag-swizzled
    // acc[r] = K[tok = n0+w16+4g+r][c = ot*16+i]
    unsigned short* kout = Ksw + (size_t)b * Nn * Cn + (size_t)kb0 * 8192
                         + ((i >> 3) & 1) * 256 + (i & 7);
    const int keyb = (w & 1) * 16 + 4 * g;      // + r
    for (int ot = 0; ot < 16; ++ot) {
      f32x4 acc = {0.f, 0.f, 0.f, 0.f};
      const unsigned short* wr = wkb + (ot * 16 + i) * Cn + 8 * g;
#pragma unroll
      for (int ks = 0; ks < 8; ++ks)
        acc = MFMA16(xf[ks], *(const f16x8*)(wr + 32 * ks), acc);
#pragma unroll
      for (int r = 0; r < 4; ++r)
        kout[ot * 512 + (keyb + r) * 8] = f2h(acc[r]);
    }
  } else {                                      // V -> frag-swizzled (V^T A-frags)
    // acc[r] = V[c = ot*16+4g+r][tok = n0+w16+i]
    unsigned short* vout = Vsw + (size_t)b * Nn * Cn + (size_t)kb0 * 8192
                         + (w & 1) * 512 + ((i >> 3) & 1) * 256 + (i & 7);
    for (int ot = 0; ot < 16; ++ot) {
      f32x4 acc = {0.f, 0.f, 0.f, 0.f};
      const unsigned short* wr = wvb + (ot * 16 + i) * Cn + 8 * g;
#pragma unroll
      for (int ks = 0; ks < 8; ++ks)
        acc = MFMA16(*(const f16x8*)(wr + 32 * ks), xf[ks], acc);
#pragma unroll
      for (int r = 0; r < 4; ++r) {
        int c = ot * 16 + 4 * g + r;
        vout[(c >> 5) * 1024 + (c & 31) * 8] = f2h(acc[r]);
      }
    }
  }
}

// ---------------- flash attention, split-K, register-direct ----------------
// grid Bn*splits*18, 256 thr = 4 waves x 32 queries. 32-key chunks. NO LDS.
// Swapped S = mfma32(Kfrag, Qfrag): lane query=l&31, keys (r&3)+8(r>>2)+4hi.
// Writes O_s = acc/l_s as fp16 P[s][b][c][n]; ml[s][b][n]={m,l} f32.
__global__ __launch_bounds__(256, 2) void attn_split(
    const unsigned short* __restrict__ Qt, const unsigned short* __restrict__ Ksw,
    const unsigned short* __restrict__ Vsw,
    unsigned short* __restrict__ P, float* __restrict__ ml, int splits) {
  const int nblk = gridDim.x;                   // divisible by 8
  const int cpx = nblk >> 3;
  const int swz = (blockIdx.x & 7) * cpx + (blockIdx.x >> 3);  // XCD chunked
  const int per_b = splits * 18;
  const int b = swz / per_b;
  const int rem = swz - b * per_b;
  const int s = rem / 18;
  const int qt = rem - s * 18;
  const int n0 = qt * 128;
  const int kn = Nn / splits, k0 = s * kn;

  const int tid = threadIdx.x, lane = tid & 63, w = tid >> 6;
  const int q = lane & 31, hi = lane >> 5;
  const int q0 = n0 + w * 32;

  // resident Q B-frags: lane: query=q, c = 16*ks + 8*hi + j
  const unsigned short* Qb = Qt + ((size_t)b * Nn + q0 + q) * Cn + 8 * hi;
  f16x8 qf[16];
#pragma unroll
  for (int ks = 0; ks < 16; ++ks) qf[ks] = *(const f16x8*)(Qb + 16 * ks);

  f32x16 acc[8];
#pragma unroll
  for (int ct = 0; ct < 8; ++ct) acc[ct] = (f32x16)(0.f);
  float m = -1e30f, lsum = 0.f;

  const unsigned short* Kb = Ksw + (size_t)b * Nn * Cn + hi * 256 + q * 8;
  const unsigned short* Vb = Vsw + (size_t)b * Nn * Cn + hi * 256 + q * 8;

  for (int jc = 0; jc < kn; jc += 32) {
    const size_t kb = (size_t)((k0 + jc) >> 5) * 8192;
    // ---- QK^T: d[key][query], 16 chained MFMAs over c=256 ----
    const unsigned short* kp = Kb + kb;
    f32x16 d = (f32x16)(0.f);
#pragma unroll
    for (int ks = 0; ks < 16; ++ks)
      d = MFMA32(*(const f16x8*)(kp + ks * 512), qf[ks], d);

    // ---- online softmax: lane owns query q, 16 scores ----
    float mx = d[0];
#pragma unroll
    for (int r = 1; r < 16; ++r) mx = fmaxf(mx, d[r]);
    mx = fmaxf(mx, __shfl_xor(mx, 32));         // full 32-key max
    if (__any(mx > m + 8.f)) {                  // defer-max (THR=8)
      float mnew = fmaxf(m, mx);
      float alpha = __expf(m - mnew);
      m = mnew;
      lsum *= alpha;
#pragma unroll
      for (int ct = 0; ct < 8; ++ct)
#pragma unroll
        for (int r = 0; r < 16; ++r) acc[ct][r] *= alpha;
    }
    float p[16];
#pragma unroll
    for (int r = 0; r < 16; ++r) p[r] = __expf(d[r] - m);
    float cs = 0.f;
#pragma unroll
    for (int r = 0; r < 16; ++r) cs += p[r];
    cs += __shfl_xor(cs, 32);
    lsum += cs;

    // ---- P -> B-frags (keys 0..15 | 16..31), half-wave exchange ----
    unsigned A0 = pk2(p[0], p[1]), A1 = pk2(p[2], p[3]);
    unsigned A2 = pk2(p[4], p[5]), A3 = pk2(p[6], p[7]);
    unsigned A4 = pk2(p[8], p[9]), A5 = pk2(p[10], p[11]);
    unsigned A6 = pk2(p[12], p[13]), A7 = pk2(p[14], p[15]);
    unsigned s0 = __shfl_xor(A0, 32), s1 = __shfl_xor(A1, 32);
    unsigned s2 = __shfl_xor(A2, 32), s3 = __shfl_xor(A3, 32);
    unsigned s4 = __shfl_xor(A4, 32), s5 = __shfl_xor(A5, 32);
    unsigned s6 = __shfl_xor(A6, 32), s7 = __shfl_xor(A7, 32);
    union { unsigned u[4]; f16x8 v; } pb0, pb1;
    pb0.u[0] = hi ? s2 : A0;  pb0.u[1] = hi ? s3 : A1;
    pb0.u[2] = hi ? A2 : s0;  pb0.u[3] = hi ? A3 : s1;
    pb1.u[0] = hi ? s6 : A4;  pb1.u[1] = hi ? s7 : A5;
    pb1.u[2] = hi ? A6 : s4;  pb1.u[3] = hi ? A7 : s5;

    // ---- PV: acc[ct] over 8 c-tiles; A = V^T frags, contiguous loads ----
    const unsigned short* vp = Vb + kb;
#pragma unroll
    for (int ct = 0; ct < 8; ++ct) {
      acc[ct] = MFMA32(*(const f16x8*)(vp + ct * 1024), pb0.v, acc[ct]);
      acc[ct] = MFMA32(*(const f16x8*)(vp + ct * 1024 + 512), pb1.v, acc[ct]);
    }
  }

  // ---- epilogue: O_s = acc/lsum -> fp16; c = 32ct + (r&3)+8*(r>>2)+4hi ----
  const float rl = 1.f / lsum;
  unsigned short* Pb = P + (size_t)(s * Bn + b) * Cn * Nn;
#pragma unroll
  for (int ct = 0; ct < 8; ++ct)
#pragma unroll
    for (int r = 0; r < 16; ++r) {
      int c = 32 * ct + (r & 3) + 8 * (r >> 2) + 4 * hi;
      Pb[(size_t)c * Nn + q0 + q] = f2h(acc[ct][r] * rl);
    }
  if (!hi)
    *(float2*)&ml[((size_t)(s * Bn + b) * Nn + q0 + q) * 2] = make_float2(m, lsum);
}

// ---------------- combine partials + residual ----------------
// out = x + sum_s w_s * O_s,  w_s = exp(m_s - M) * l_s / sum(exp(m_s-M) l_s).
__global__ __launch_bounds__(256) void combine_k(
    const float* __restrict__ x, const unsigned short* __restrict__ P,
    const float* __restrict__ ml, float* __restrict__ out, int splits) {
  __shared__ float sc[4][32];
  const int tpb = Nn / 32;                      // 72
  const int b = blockIdx.x / tpb;
  const int n0 = (blockIdx.x - b * tpb) * 32;
  const int t = threadIdx.x;
  if (t < 32) {
    const int n = n0 + t;
    const size_t sstr = (size_t)Bn * Nn * 2;
    const float* mlb = ml + ((size_t)b * Nn + n) * 2;
    float m0 = mlb[0], l0 = mlb[1];
    float m1 = -1e30f, l1 = 0.f, m2 = -1e30f, l2 = 0.f, m3 = -1e30f, l3 = 0.f;
    if (splits > 1) { m1 = mlb[sstr]; l1 = mlb[sstr + 1]; }
    if (splits > 2) { m2 = mlb[2 * sstr]; l2 = mlb[2 * sstr + 1]; }
    if (splits > 3) { m3 = mlb[3 * sstr]; l3 = mlb[3 * sstr + 1]; }
    float M = fmaxf(fmaxf(m0, m1), fmaxf(m2, m3));
    float g0 = __expf(m0 - M) * l0, g1 = __expf(m1 - M) * l1;
    float g2 = __expf(m2 - M) * l2, g3 = __expf(m3 - M) * l3;
    float rden = 1.f / (g0 + g1 + g2 + g3);
    sc[0][t] = g0 * rden; sc[1][t] = g1 * rden;
    sc[2][t] = g2 * rden; sc[3][t] = g3 * rden;
  }
  __syncthreads();
  const int nl4 = (t & 7) * 4, c0 = t >> 3;
  const size_t pstr = (size_t)Bn * Cn * Nn;     // shorts per split
  const float* xb = x + (size_t)b * Cn * Nn;
  float* ob = out + (size_t)b * Cn * Nn;
#pragma unroll
  for (int k = 0; k < 8; ++k) {
    const int c = c0 + 32 * k;
    const unsigned short* Pp = P + ((size_t)b * Cn + c) * Nn + n0 + nl4;
    f32x4 a = {0.f, 0.f, 0.f, 0.f};
    for (int s2 = 0; s2 < splits; ++s2) {
      ushort4 ph = *(const ushort4*)(Pp + s2 * pstr);
      float sv = sc[s2][nl4 + 0];               // same weight row-group of 4
      f32x4 pv = {h2f(ph.x), h2f(ph.y), h2f(ph.z), h2f(ph.w)};
      f32x4 sw = {sc[s2][nl4 + 0], sc[s2][nl4 + 1], sc[s2][nl4 + 2], sc[s2][nl4 + 3]};
      (void)sv;
      a += sw * pv;
    }
    f32x4 xv = *(const f32x4*)(xb + (size_t)c * Nn + n0 + nl4);
    *(f32x4*)(ob + (size_t)c * Nn + n0 + nl4) = xv + a;
  }
}

extern "C" void kernel_launch(void* const* d_in, const int* in_sizes, int n_in,
                              void* d_out, int out_size, void* d_ws, size_t ws_size,
                              hipStream_t stream) {
  const float* x = (const float*)d_in[0];
  const float* wq = (const float*)d_in[1];
  const float* wk = (const float*)d_in[2];
  const float* wv = (const float*)d_in[3];
  float* out = (float*)d_out;

  unsigned short* wqb = (unsigned short*)d_ws;
  unsigned short* wkb = wqb + Cn * Cn;
  unsigned short* wvb = wkb + Cn * Cn;
  unsigned short* Qt = wvb + Cn * Cn;
  unsigned short* Ksw = Qt + (size_t)Bn * Nn * Cn;
  unsigned short* Vsw = Ksw + (size_t)Bn * Nn * Cn;
  unsigned short* P = Vsw + (size_t)Bn * Nn * Cn;

  const size_t baseB = (size_t)(3 * Cn * Cn + 3 * (size_t)Bn * Nn * Cn) * 2;
  const size_t perSplitB = (size_t)Bn * Nn * Cn * 2 + (size_t)Bn * Nn * 2 * 4;

  int splits = 1;
  if (baseB + 4 * perSplitB <= ws_size) splits = 4;
  else if (baseB + 2 * perSplitB <= ws_size) splits = 2;

  float* ml = (float*)(P + (size_t)splits * Bn * Nn * Cn);

  hipLaunchKernelGGL(cvt_w, dim3(3 * Cn * Cn / 256), dim3(256), 0, stream, wq, wk, wv, wqb);
  hipLaunchKernelGGL(qkv_proj, dim3(Nn / 64, Bn, 3), dim3(256), 0, stream,
                     x, wqb, wkb, wvb, Qt, Ksw, Vsw);
  hipLaunchKernelGGL(attn_split, dim3(Bn * splits * 18), dim3(256), 0, stream,
                     Qt, Ksw, Vsw, P, ml, splits);
  hipLaunchKernelGGL(combine_k, dim3(Bn * Nn / 32), dim3(256), 0, stream,
                     x, P, ml, out, splits);
}